// Round 6
// baseline (366.190 us; speedup 1.0000x reference)
//
#include <hip/hip_runtime.h>
#include <hip/hip_bf16.h>
#include <math.h>

// NeuroManifoldBlock: sdr_proj -> LN1 -> FHN-causal-attn -> +res -> LN2 -> SwiGLU -> +res
// B=2 T=1024 SDR=2048 D=1024 H=16 DH=64 FFN_H=2730 (padded 2816)
// R6: (a) attn strip-pairing: block = (strip 63-pr, strip pr) sequentially ->
//     exactly 17 KV-tiles per block (uniform load, was 1..16); 1024 blocks.
//     (b) k_gemm/k_gemm64: double-buffered LDS prefetch K-loop (stage t+1
//     before compute t, one barrier/K-step) — grids are 1-1.5 blocks/CU so
//     staging latency was fully exposed; prefetch overlaps it with MFMA.

typedef __bf16 bf16;
typedef __bf16 bf16x4 __attribute__((ext_vector_type(4)));
typedef __bf16 bf16x8 __attribute__((ext_vector_type(8)));
typedef float  f32x4  __attribute__((ext_vector_type(4)));

#define DEV __device__ __forceinline__

DEV void gload_lds16(const void* g, void* l) {
  __builtin_amdgcn_global_load_lds(
      (const __attribute__((address_space(1))) void*)g,
      (__attribute__((address_space(3))) void*)l, 16, 0, 0);
}

// ---------------------------------------------------------------- converts
__global__ __launch_bounds__(256) void k_convert(const float* __restrict__ in,
                                                 bf16* __restrict__ out, int n) {
  int i = (blockIdx.x * 256 + threadIdx.x) * 4;
  if (i < n) {
    float4 f = *(const float4*)(in + i);
    bf16x4 o;
    o[0] = (bf16)f.x; o[1] = (bf16)f.y; o[2] = (bf16)f.z; o[3] = (bf16)f.w;
    *(bf16x4*)(out + i) = o;
  }
}

// in: fp32 [K][N] row-major -> out: bf16 [Npad][Kpad] (transposed, zero-padded)
__global__ __launch_bounds__(256) void k_transpose_wt(const float* __restrict__ in,
    bf16* __restrict__ out, int K, int N, int Kpad, int Npad) {
  __shared__ float tile[32][33];
  const int kb = blockIdx.x * 32, nb = blockIdx.y * 32;
  const int tx = threadIdx.x & 31, ty = threadIdx.x >> 5;   // 32 x 8
  for (int i = ty; i < 32; i += 8) {
    int k = kb + i, n = nb + tx;
    tile[i][tx] = (k < K && n < N) ? in[(size_t)k * N + n] : 0.f;
  }
  __syncthreads();
  for (int i = ty; i < 32; i += 8) {
    int n = nb + i, k = kb + tx;
    if (n < Npad && k < Kpad) out[(size_t)n * Kpad + k] = (bf16)tile[tx][i];
  }
}

// ---------------------------------------------------------------- layernorm
__global__ __launch_bounds__(256) void k_layernorm(const float* __restrict__ x,
    const float* __restrict__ gw, const float* __restrict__ bw, bf16* __restrict__ out) {
  const int row = blockIdx.x;           // 2048 rows, D=1024, 4 elems/thread
  const int t = threadIdx.x;
  const float* xr = x + (size_t)row * 1024;
  float4 f = *(const float4*)(xr + t * 4);
  float s  = f.x + f.y + f.z + f.w;
  float s2 = f.x * f.x + f.y * f.y + f.z * f.z + f.w * f.w;
  #pragma unroll
  for (int o = 32; o > 0; o >>= 1) { s += __shfl_down(s, o, 64); s2 += __shfl_down(s2, o, 64); }
  __shared__ float rA[4], rB[4];
  const int wid = t >> 6;
  if ((t & 63) == 0) { rA[wid] = s; rB[wid] = s2; }
  __syncthreads();
  s  = rA[0] + rA[1] + rA[2] + rA[3];
  s2 = rB[0] + rB[1] + rB[2] + rB[3];
  const float mu   = s * (1.f / 1024.f);
  const float var  = fmaxf(s2 * (1.f / 1024.f) - mu * mu, 0.f);
  const float rstd = rsqrtf(var + 1e-5f);
  float4 g4 = *(const float4*)(gw + t * 4);
  float4 b4 = *(const float4*)(bw + t * 4);
  bf16x4 o4;
  o4[0] = (bf16)((f.x - mu) * rstd * g4.x + b4.x);
  o4[1] = (bf16)((f.y - mu) * rstd * g4.y + b4.y);
  o4[2] = (bf16)((f.z - mu) * rstd * g4.z + b4.z);
  o4[3] = (bf16)((f.w - mu) * rstd * g4.w + b4.w);
  *(bf16x4*)(out + (size_t)row * 1024 + t * 4) = o4;
}

// ---------------------------------------------------------------- GEMMs (A[M][K] x Bt[N][K])
enum { EPI_BIAS = 1, EPI_BIAS_RES = 2, EPI_RES = 3, EPI_QKV = 5 };

template <int EPI>
DEV void gemm_epilogue(int rb, int cc, int Nn, const f32x4& a,
                       float* C, const float* bias, const float* res,
                       bf16* qp, bf16* kp, float* vbuf) {
  float bv = 0.f;
  if constexpr (EPI == EPI_BIAS || EPI == EPI_BIAS_RES || EPI == EPI_QKV) bv = bias[cc];
  #pragma unroll
  for (int v = 0; v < 4; ++v) {
    const int row = rb + v;
    float val = a[v] + bv;
    if constexpr (EPI == EPI_QKV) {
      const int bq = row >> 10, tt = row & 1023;
      if (cc < 1024) {        // q, pre-scaled by 1/sqrt(64)
        qp[(size_t)(bq * 16 + (cc >> 6)) * 65536 + (size_t)tt * 64 + (cc & 63)] = (bf16)(val * 0.125f);
      } else if (cc < 2048) { // k
        const int c2 = cc - 1024;
        kp[(size_t)(bq * 16 + (c2 >> 6)) * 65536 + (size_t)tt * 64 + (c2 & 63)] = (bf16)val;
      } else {                // v -> compact fp32 buffer [2048][1024]
        vbuf[(size_t)row * 1024 + (cc - 2048)] = val;
      }
    } else {
      const size_t idx = (size_t)row * Nn + cc;
      if constexpr (EPI == EPI_BIAS_RES || EPI == EPI_RES) val += res[idx];
      C[idx] = val;
    }
  }
}

// 128x128 tile, 4 waves (2x2 of 64x64), double-buffered LDS prefetch
template <int EPI>
__global__ __launch_bounds__(256, 2)
void k_gemm(const bf16* __restrict__ A, const bf16* __restrict__ Bt,
            float* __restrict__ C, const float* __restrict__ bias,
            const float* __restrict__ res, bf16* __restrict__ qp,
            bf16* __restrict__ kp, float* __restrict__ vbuf, int Nn, int Kk) {
  __shared__ __align__(16) bf16 As[2][128 * 64];
  __shared__ __align__(16) bf16 Bs[2][128 * 64];
  const int t = threadIdx.x;
  const int lane = t & 63, wid = t >> 6;
  const int wr = wid >> 1, wc = wid & 1;
  const int row0 = blockIdx.y * 128, col0 = blockIdx.x * 128;
  const int g  = t & 7;
  const int r0 = t >> 3;
  const int c16s = g ^ (r0 & 7);                      // pre-swizzled source group
  f32x4 acc[4][4] = {};

  auto stage = [&](int buf, int k0) {
    #pragma unroll
    for (int it = 0; it < 4; ++it) {
      int r = r0 + it * 32;
      gload_lds16(A + (size_t)(row0 + r) * Kk + k0 + c16s * 8, &As[buf][(it * 256 + wid * 64) * 8]);
    }
    #pragma unroll
    for (int it = 0; it < 4; ++it) {
      int r = r0 + it * 32;
      gload_lds16(Bt + (size_t)(col0 + r) * Kk + k0 + c16s * 8, &Bs[buf][(it * 256 + wid * 64) * 8]);
    }
  };

  stage(0, 0);
  __syncthreads();                                    // buf0 resident
  int cur = 0;
  for (int k0 = 0; k0 < Kk; k0 += 64) {
    if (k0 + 64 < Kk) stage(cur ^ 1, k0 + 64);        // prefetch next tile
    #pragma unroll
    for (int ks = 0; ks < 2; ++ks) {
      bf16x8 af[4], bfv[4];
      #pragma unroll
      for (int m = 0; m < 4; ++m) {
        int rr = wr * 64 + m * 16 + (lane & 15);
        int c16 = (ks * 4 + (lane >> 4)) ^ (rr & 7);
        af[m] = *(const bf16x8*)&As[cur][rr * 64 + c16 * 8];
      }
      #pragma unroll
      for (int n = 0; n < 4; ++n) {
        int rr = wc * 64 + n * 16 + (lane & 15);
        int c16 = (ks * 4 + (lane >> 4)) ^ (rr & 7);
        bfv[n] = *(const bf16x8*)&Bs[cur][rr * 64 + c16 * 8];
      }
      #pragma unroll
      for (int m = 0; m < 4; ++m)
        #pragma unroll
        for (int n = 0; n < 4; ++n)
          acc[m][n] = __builtin_amdgcn_mfma_f32_16x16x32_bf16(af[m], bfv[n], acc[m][n], 0, 0, 0);
    }
    __syncthreads();                                  // drains prefetch, guards reuse
    cur ^= 1;
  }
  #pragma unroll
  for (int m = 0; m < 4; ++m) {
    const int rb = row0 + wr * 64 + m * 16 + ((lane >> 4) << 2);
    #pragma unroll
    for (int n = 0; n < 4; ++n) {
      const int cc = col0 + wc * 64 + n * 16 + (lane & 15);
      gemm_epilogue<EPI>(rb, cc, Nn, acc[m][n], C, bias, res, qp, kp, vbuf);
    }
  }
}

// 128x64 tile, 4 waves stacked in M (wave = 32x64), double-buffered prefetch
template <int EPI>
__global__ __launch_bounds__(256, 2)
void k_gemm64(const bf16* __restrict__ A, const bf16* __restrict__ Bt,
              float* __restrict__ C, const float* __restrict__ bias,
              const float* __restrict__ res, int Nn, int Kk) {
  __shared__ __align__(16) bf16 As[2][128 * 64];
  __shared__ __align__(16) bf16 Bs[2][64 * 64];
  const int t = threadIdx.x;
  const int lane = t & 63, wid = t >> 6;
  const int row0 = blockIdx.y * 128, col0 = blockIdx.x * 64;
  const int g  = t & 7;
  const int r0 = t >> 3;
  const int c16s = g ^ (r0 & 7);
  f32x4 acc[2][4] = {};

  auto stage = [&](int buf, int k0) {
    #pragma unroll
    for (int it = 0; it < 4; ++it) {
      int r = r0 + it * 32;
      gload_lds16(A + (size_t)(row0 + r) * Kk + k0 + c16s * 8, &As[buf][(it * 256 + wid * 64) * 8]);
    }
    #pragma unroll
    for (int it = 0; it < 2; ++it) {
      int r = r0 + it * 32;
      gload_lds16(Bt + (size_t)(col0 + r) * Kk + k0 + c16s * 8, &Bs[buf][(it * 256 + wid * 64) * 8]);
    }
  };

  stage(0, 0);
  __syncthreads();
  int cur = 0;
  for (int k0 = 0; k0 < Kk; k0 += 64) {
    if (k0 + 64 < Kk) stage(cur ^ 1, k0 + 64);
    #pragma unroll
    for (int ks = 0; ks < 2; ++ks) {
      bf16x8 af[2], bfv[4];
      #pragma unroll
      for (int m = 0; m < 2; ++m) {
        int rr = wid * 32 + m * 16 + (lane & 15);
        int c16 = (ks * 4 + (lane >> 4)) ^ (rr & 7);
        af[m] = *(const bf16x8*)&As[cur][rr * 64 + c16 * 8];
      }
      #pragma unroll
      for (int n = 0; n < 4; ++n) {
        int rr = n * 16 + (lane & 15);
        int c16 = (ks * 4 + (lane >> 4)) ^ (rr & 7);
        bfv[n] = *(const bf16x8*)&Bs[cur][rr * 64 + c16 * 8];
      }
      #pragma unroll
      for (int m = 0; m < 2; ++m)
        #pragma unroll
        for (int n = 0; n < 4; ++n)
          acc[m][n] = __builtin_amdgcn_mfma_f32_16x16x32_bf16(af[m], bfv[n], acc[m][n], 0, 0, 0);
    }
    __syncthreads();
    cur ^= 1;
  }
  #pragma unroll
  for (int m = 0; m < 2; ++m) {
    const int rb = row0 + wid * 32 + m * 16 + ((lane >> 4) << 2);
    #pragma unroll
    for (int n = 0; n < 4; ++n) {
      const int cc = col0 + n * 16 + (lane & 15);
      gemm_epilogue<EPI>(rb, cc, Nn, acc[m][n], C, bias, res, nullptr, nullptr, nullptr);
    }
  }
}

// Fused SwiGLU GEMM: act = silu(A.Bg^T) * (A.Bu^T), A staged once, both accs live.
// Single-buffered (32 MFMA/K-step already hides staging better; 96KB dbuf would
// drop to 1 block/CU).
__global__ __launch_bounds__(256, 2)
void k_gemm_swiglu(const bf16* __restrict__ A, const bf16* __restrict__ Bg,
                   const bf16* __restrict__ Bu, bf16* __restrict__ act,
                   int Nn, int Kk) {
  __shared__ __align__(16) bf16 As[128 * 64];
  __shared__ __align__(16) bf16 Bgs[128 * 64];
  __shared__ __align__(16) bf16 Bus[128 * 64];
  const int t = threadIdx.x;
  const int lane = t & 63, wid = t >> 6;
  const int wr = wid >> 1, wc = wid & 1;
  const int row0 = blockIdx.y * 128, col0 = blockIdx.x * 128;
  const int g  = t & 7;
  const int r0 = t >> 3;
  const int c16s = g ^ (r0 & 7);
  f32x4 ag[4][4] = {}, au[4][4] = {};

  for (int k0 = 0; k0 < Kk; k0 += 64) {
    #pragma unroll
    for (int it = 0; it < 4; ++it) {
      int r = r0 + it * 32;
      gload_lds16(A + (size_t)(row0 + r) * Kk + k0 + c16s * 8, &As[(it * 256 + wid * 64) * 8]);
    }
    #pragma unroll
    for (int it = 0; it < 4; ++it) {
      int r = r0 + it * 32;
      gload_lds16(Bg + (size_t)(col0 + r) * Kk + k0 + c16s * 8, &Bgs[(it * 256 + wid * 64) * 8]);
    }
    #pragma unroll
    for (int it = 0; it < 4; ++it) {
      int r = r0 + it * 32;
      gload_lds16(Bu + (size_t)(col0 + r) * Kk + k0 + c16s * 8, &Bus[(it * 256 + wid * 64) * 8]);
    }
    __syncthreads();
    #pragma unroll
    for (int ks = 0; ks < 2; ++ks) {
      bf16x8 af[4], bg[4], bu[4];
      #pragma unroll
      for (int m = 0; m < 4; ++m) {
        int rr = wr * 64 + m * 16 + (lane & 15);
        int c16 = (ks * 4 + (lane >> 4)) ^ (rr & 7);
        af[m] = *(const bf16x8*)&As[rr * 64 + c16 * 8];
      }
      #pragma unroll
      for (int n = 0; n < 4; ++n) {
        int rr = wc * 64 + n * 16 + (lane & 15);
        int c16 = (ks * 4 + (lane >> 4)) ^ (rr & 7);
        bg[n] = *(const bf16x8*)&Bgs[rr * 64 + c16 * 8];
        bu[n] = *(const bf16x8*)&Bus[rr * 64 + c16 * 8];
      }
      #pragma unroll
      for (int m = 0; m < 4; ++m)
        #pragma unroll
        for (int n = 0; n < 4; ++n) {
          ag[m][n] = __builtin_amdgcn_mfma_f32_16x16x32_bf16(af[m], bg[n], ag[m][n], 0, 0, 0);
          au[m][n] = __builtin_amdgcn_mfma_f32_16x16x32_bf16(af[m], bu[n], au[m][n], 0, 0, 0);
        }
    }
    __syncthreads();
  }
  #pragma unroll
  for (int m = 0; m < 4; ++m) {
    const int rb = row0 + wr * 64 + m * 16 + ((lane >> 4) << 2);
    #pragma unroll
    for (int n = 0; n < 4; ++n) {
      const int cc = col0 + wc * 64 + n * 16 + (lane & 15);
      #pragma unroll
      for (int v = 0; v < 4; ++v) {
        float gt = ag[m][n][v], up = au[m][n][v];
        float sg = gt / (1.f + __expf(-gt));
        act[(size_t)(rb + v) * Nn + cc] = (bf16)(sg * up);
      }
    }
  }
}

// v fp32 [2048][1024] -> vT bf16 [32 bh][64 d][1024 t]
__global__ __launch_bounds__(256) void k_transpose_v(const float* __restrict__ vbuf,
                                                     bf16* __restrict__ vT) {
  __shared__ float tile[32][33];
  const int bh = blockIdx.z, b = bh >> 4, h = bh & 15;
  const int t0 = blockIdx.x * 32, d0 = blockIdx.y * 32;
  const int tx = threadIdx.x & 31, ty = threadIdx.x >> 5;
  for (int i = ty; i < 32; i += 8)
    tile[i][tx] = vbuf[(size_t)(b * 1024 + t0 + i) * 1024 + h * 64 + d0 + tx];
  __syncthreads();
  for (int i = ty; i < 32; i += 8)
    vT[(size_t)bh * 65536 + (size_t)(d0 + i) * 1024 + t0 + tx] = (bf16)tile[tx][i];
}

// ---------------------------------------------------------------- FHN flash attention
// Strip-paired: block (pr, bh) processes strip 63-pr then strip pr sequentially;
// jn(63-pr)+jn(pr) = 17 KV tiles for EVERY block -> uniform load. Per phase:
// 4 waves split KV tiles (j = wid, wid+4, ...) with private softmax state +
// private P buffer; two barriers + LDS merge at phase end.
#define FHN_DT 0.1f
#define FHN_A_ 0.7f

__global__ __launch_bounds__(256, 4)
void k_attn(const bf16* __restrict__ q, const bf16* __restrict__ k,
            const bf16* __restrict__ vT, bf16* __restrict__ ctx) {
  // union: [0,8KB) = 4x per-wave Ps (bf16 16x64); at merge:
  // [0,16KB) = comb f32[4][16][64], [16KB,16.5KB) = ml f32[4][16][2]
  __shared__ __align__(16) char smem[16896];
  const int bx = blockIdx.x;
  const int pr = bx >> 5;                     // pair id 0..31
  const int bh = bx & 31;
  const int b = bh >> 4, hh = bh & 15;
  const int t = threadIdx.x;
  const int lane = t & 63, wid = t >> 6;
  const int l15 = lane & 15, g4 = lane >> 4;
  bf16* Ps    = (bf16*)smem + wid * 1024;
  float* comb = (float*)smem;
  float* mlb  = (float*)(smem + 16384);
  const bf16* qb = q  + (size_t)bh * 65536;
  const bf16* kb = k  + (size_t)bh * 65536;
  const bf16* vb = vT + (size_t)bh * 65536;
  const float wden = 1.0f / (1.0f + FHN_DT * 0.8f / 12.5f);
  const float dtau = FHN_DT / 12.5f;

  #pragma unroll 1
  for (int ph = 0; ph < 2; ++ph) {
    const int s  = ph ? pr : 63 - pr;         // heavy strip first
    const int q0 = s * 16;
    // Q fragments (A-layout: row=l15, k=g4*8+e per 32-chunk), q pre-scaled
    bf16x8 qf[2];
    #pragma unroll
    for (int ks = 0; ks < 2; ++ks)
      qf[ks] = *(const bf16x8*)(qb + (size_t)(q0 + l15) * 64 + ks * 32 + g4 * 8);

    f32x4 o[4] = {};
    f32x4 mrow = {-1e30f, -1e30f, -1e30f, -1e30f};
    f32x4 ssum = {0.f, 0.f, 0.f, 0.f};
    const int jn = (q0 >> 6) + 1;

    for (int j = wid; j < jn; j += 4) {
      const int kv0 = j * 64;
      // S = Q . K^T ; B-frag from K[kv][d] rows (16B contiguous in d)
      f32x4 sc[4] = {};
      #pragma unroll
      for (int ks = 0; ks < 2; ++ks)
        #pragma unroll
        for (int n = 0; n < 4; ++n) {
          bf16x8 kf = *(const bf16x8*)(kb + (size_t)(kv0 + n * 16 + l15) * 64 + ks * 32 + g4 * 8);
          sc[n] = __builtin_amdgcn_mfma_f32_16x16x32_bf16(qf[ks], kf, sc[n], 0, 0, 0);
        }
      // FHN IMEX + threshold + causal mask (only tile jn-1 straddles diagonal)
      const int rbase = q0 + (g4 << 2);
      #pragma unroll
      for (int n = 0; n < 4; ++n)
        #pragma unroll
        for (int v = 0; v < 4; ++v) {
          float sv = sc[n][v];
          float vv = sv, ww = 0.f;
          #pragma unroll
          for (int st = 0; st < 4; ++st) {
            vv = vv + FHN_DT * (vv - vv * vv * vv * (1.f / 3.f) - ww + sv);
            ww = (ww + dtau * (vv + FHN_A_)) * wden;
          }
          float lg = vv - 0.5f;
          if (j == jn - 1) {
            int kvi = kv0 + n * 16 + l15;
            if (kvi > rbase + v) lg = -1e9f;
          }
          sc[n][v] = lg;
        }
      // online softmax (rows live in 16-lane groups)
      f32x4 mnew, scl;
      #pragma unroll
      for (int v = 0; v < 4; ++v) {
        float m0 = fmaxf(fmaxf(sc[0][v], sc[1][v]), fmaxf(sc[2][v], sc[3][v]));
        #pragma unroll
        for (int msk = 1; msk < 16; msk <<= 1) m0 = fmaxf(m0, __shfl_xor(m0, msk, 64));
        mnew[v] = fmaxf(mrow[v], m0);
        scl[v] = __expf(mrow[v] - mnew[v]);
      }
      #pragma unroll
      for (int v = 0; v < 4; ++v) {
        float rs = 0.f;
        #pragma unroll
        for (int n = 0; n < 4; ++n) {
          float p = __expf(sc[n][v] - mnew[v]);
          sc[n][v] = p;
          rs += p;
        }
        #pragma unroll
        for (int msk = 1; msk < 16; msk <<= 1) rs += __shfl_xor(rs, msk, 64);
        ssum[v] = ssum[v] * scl[v] + rs;
        mrow[v] = mnew[v];
      }
      #pragma unroll
      for (int n = 0; n < 4; ++n) o[n] *= scl;
      // P -> bf16 -> per-wave swizzled LDS (wave-local RAW)
      #pragma unroll
      for (int n = 0; n < 4; ++n)
        #pragma unroll
        for (int v = 0; v < 4; ++v) {
          int rr = (g4 << 2) + v;
          int c = n * 16 + l15;
          int c16 = (c >> 3) ^ (rr & 7);
          Ps[rr * 64 + c16 * 8 + (c & 7)] = (bf16)sc[n][v];
        }
      // O += P . V   (B-frag from vT[d][t], 16B contiguous in t)
      #pragma unroll
      for (int ks = 0; ks < 2; ++ks) {
        int c16 = (ks * 4 + g4) ^ (l15 & 7);
        bf16x8 pa = *(const bf16x8*)&Ps[l15 * 64 + c16 * 8];
        #pragma unroll
        for (int n = 0; n < 4; ++n) {
          bf16x8 vf = *(const bf16x8*)(vb + (size_t)(n * 16 + l15) * 1024 + kv0 + ks * 32 + g4 * 8);
          o[n] = __builtin_amdgcn_mfma_f32_16x16x32_bf16(pa, vf, o[n], 0, 0, 0);
        }
      }
    }
    __syncthreads();               // all Ps reads done -> comb may overwrite
    // write partials (empty waves contribute m=-1e30, l=0, o=0 -> factor 0)
    #pragma unroll
    for (int n = 0; n < 4; ++n)
      #pragma unroll
      for (int v = 0; v < 4; ++v)
        comb[(wid * 16 + (g4 << 2) + v) * 64 + n * 16 + l15] = o[n][v];
    if (l15 == 0) {
      #pragma unroll
      for (int v = 0; v < 4; ++v) {
        mlb[(wid * 16 + (g4 << 2) + v) * 2 + 0] = mrow[v];
        mlb[(wid * 16 + (g4 << 2) + v) * 2 + 1] = ssum[v];
      }
    }
    __syncthreads();
    // merge: thread t handles (row = t>>4, 4 d-values at dseg = t&15)
    {
      const int row = t >> 4, dseg = t & 15;
      float m = mlb[row * 2];
      #pragma unroll
      for (int w = 1; w < 4; ++w) m = fmaxf(m, mlb[(w * 16 + row) * 2]);
      float L = 0.f;
      f32x4 a = {0.f, 0.f, 0.f, 0.f};
      #pragma unroll
      for (int w = 0; w < 4; ++w) {
        float f = __expf(mlb[(w * 16 + row) * 2] - m);
        L += f * mlb[(w * 16 + row) * 2 + 1];
        f32x4 c = *(const f32x4*)&comb[(w * 16 + row) * 64 + dseg * 4];
        a += c * f;
      }
      const float inv = 1.f / L;
      bf16x4 o4;
      o4[0] = (bf16)(a[0] * inv); o4[1] = (bf16)(a[1] * inv);
      o4[2] = (bf16)(a[2] * inv); o4[3] = (bf16)(a[3] * inv);
      *(bf16x4*)&ctx[(size_t)(b * 1024 + q0 + row) * 1024 + hh * 64 + dseg * 4] = o4;
    }
    __syncthreads();               // merge reads done before next phase's Ps writes
  }
}

// ---------------------------------------------------------------- launch
extern "C" void kernel_launch(void* const* d_in, const int* in_sizes, int n_in,
                              void* d_out, int out_size, void* d_ws, size_t ws_size,
                              hipStream_t stream) {
  (void)in_sizes; (void)n_in; (void)out_size; (void)ws_size;
  const float* sdr    = (const float*)d_in[0];
  const float* sdr_w  = (const float*)d_in[1];
  const float* sdr_b  = (const float*)d_in[2];
  const float* w_qkv  = (const float*)d_in[3];
  const float* b_qkv  = (const float*)d_in[4];
  const float* w_out  = (const float*)d_in[5];
  const float* b_out  = (const float*)d_in[6];
  const float* ln1_g  = (const float*)d_in[7];
  const float* ln1_b  = (const float*)d_in[8];
  const float* ln2_g  = (const float*)d_in[9];
  const float* ln2_b  = (const float*)d_in[10];
  const float* w_gate = (const float*)d_in[11];
  const float* w_up   = (const float*)d_in[12];
  const float* w_down = (const float*)d_in[13];
  float* out = (float*)d_out;

  char* wsb = (char*)d_ws;
  size_t off = 0;
  auto alloc = [&](size_t bytes) -> void* {
    void* p = (void*)(wsb + off);
    off += (bytes + 255) & ~(size_t)255;
    return p;
  };
  bf16* sdr_w_t  = (bf16*)alloc(1024ull * 2048 * 2);
  bf16* w_qkv_t  = (bf16*)alloc(3072ull * 1024 * 2);
  bf16* w_out_t  = (bf16*)alloc(1024ull * 1024 * 2);
  bf16* w_gate_t = (bf16*)alloc(2816ull * 1024 * 2);
  bf16* w_up_t   = (bf16*)alloc(2816ull * 1024 * 2);
  bf16* w_down_t = (bf16*)alloc(1024ull * 2816 * 2);
  bf16* big_bf   = (bf16*)alloc(2048ull * 2816 * 2);  // sdr_bf16 then act (time-shared)
  bf16* sdr_bf   = big_bf;
  bf16* act      = big_bf;
  float* x       = (float*)alloc(2048ull * 1024 * 4);
  bf16*  h       = (bf16*)alloc(2048ull * 1024 * 2);  // h1 then h2 (time-shared)
  float* vbuf    = (float*)alloc(2048ull * 1024 * 4);
  bf16*  qb      = (bf16*)alloc(32ull * 1024 * 64 * 2);
  bf16*  kb      = (bf16*)alloc(32ull * 1024 * 64 * 2);
  bf16*  vT      = (bf16*)alloc(32ull * 1024 * 64 * 2);
  bf16*  ctx     = (bf16*)alloc(2048ull * 1024 * 2);
  float* x2      = (float*)alloc(2048ull * 1024 * 4);

  // weight transposes + activations to bf16
  k_convert<<<4096, 256, 0, stream>>>(sdr, sdr_bf, 4194304);
  k_transpose_wt<<<dim3(64, 32),  256, 0, stream>>>(sdr_w,  sdr_w_t,  2048, 1024, 2048, 1024);
  k_transpose_wt<<<dim3(32, 96),  256, 0, stream>>>(w_qkv,  w_qkv_t,  1024, 3072, 1024, 3072);
  k_transpose_wt<<<dim3(32, 32),  256, 0, stream>>>(w_out,  w_out_t,  1024, 1024, 1024, 1024);
  k_transpose_wt<<<dim3(32, 88),  256, 0, stream>>>(w_gate, w_gate_t, 1024, 2730, 1024, 2816);
  k_transpose_wt<<<dim3(32, 88),  256, 0, stream>>>(w_up,   w_up_t,   1024, 2730, 1024, 2816);
  k_transpose_wt<<<dim3(88, 32),  256, 0, stream>>>(w_down, w_down_t, 2730, 1024, 2816, 1024);

  // x = sdr @ sdr_w + sdr_b
  k_gemm64<EPI_BIAS><<<dim3(16, 16), 256, 0, stream>>>(sdr_bf, sdr_w_t, x, sdr_b, nullptr, 1024, 2048);
  k_layernorm<<<2048, 256, 0, stream>>>(x, ln1_g, ln1_b, h);
  // qkv GEMM with fused split: q,k bf16 [bh][t][d] (q pre-scaled), v fp32 compact
  k_gemm<EPI_QKV><<<dim3(24, 16), 256, 0, stream>>>(h, w_qkv_t, nullptr, b_qkv, nullptr, qb, kb, vbuf, 3072, 1024);
  k_transpose_v<<<dim3(32, 2, 32), 256, 0, stream>>>(vbuf, vT);
  // FHN flash attention (32 strip-pairs x 32 bh, uniform 17 tiles/block)
  k_attn<<<1024, 256, 0, stream>>>(qb, kb, vT, ctx);
  // x2 = x + ctx @ w_out + b_out
  k_gemm64<EPI_BIAS_RES><<<dim3(16, 16), 256, 0, stream>>>(ctx, w_out_t, x2, b_out, x, 1024, 1024);
  k_layernorm<<<2048, 256, 0, stream>>>(x2, ln2_g, ln2_b, h);
  // act = silu(h2 @ w_gate) * (h2 @ w_up)  (fused, A staged once)
  k_gemm_swiglu<<<dim3(22, 16), 256, 0, stream>>>(h, w_gate_t, w_up_t, act, 2816, 1024);
  // out = x2 + act @ w_down
  k_gemm64<EPI_RES><<<dim3(16, 16), 256, 0, stream>>>(act, w_down_t, out, nullptr, x2, 1024, 2816);
}

// Round 7
// 328.150 us; speedup vs baseline: 1.1159x; 1.1159x over previous
//
#include <hip/hip_runtime.h>
#include <hip/hip_bf16.h>
#include <math.h>

// NeuroManifoldBlock: sdr_proj -> LN1 -> FHN-causal-attn -> +res -> LN2 -> SwiGLU -> +res
// B=2 T=1024 SDR=2048 D=1024 H=16 DH=64 FFN_H=2730 (padded 2816)
// R7: (a) attn reverted to R5 (strip-pairing cost +10us and 30MB spill traffic);
//     (b) ALL prep (convert + 6 weight transposes) fused into ONE k_prep kernel
//     with bf16x8 stores (was 18 launches -> 10; old transpose wrote 64B segs);
//     (c) GEMMs unchanged (dbuf, measured neutral).

typedef __bf16 bf16;
typedef __bf16 bf16x4 __attribute__((ext_vector_type(4)));
typedef __bf16 bf16x8 __attribute__((ext_vector_type(8)));
typedef float  f32x4  __attribute__((ext_vector_type(4)));

#define DEV __device__ __forceinline__

DEV void gload_lds16(const void* g, void* l) {
  __builtin_amdgcn_global_load_lds(
      (const __attribute__((address_space(1))) void*)g,
      (__attribute__((address_space(3))) void*)l, 16, 0, 0);
}

// ---------------------------------------------------------------- fused prep
// blocks 0..511: sdr fp32->bf16 copy (8192 elems/block)
// then 64x64 transpose tiles: in fp32 [K][N] -> out bf16 [Npad][Kpad], zero-pad.
// region: [512,1024) sdr_w | [1024,1792) w_qkv | [1792,2048) w_out
//         [2048,2752) w_gate | [2752,3456) w_up | [3456,4160) w_down
struct PrepT { const float* in; bf16* out; int K, N, Kpad, nnb; };

__global__ __launch_bounds__(256)
void k_prep(const float* __restrict__ sdr, bf16* __restrict__ sdr_bf,
            const float* __restrict__ sdr_w, const float* __restrict__ w_qkv,
            const float* __restrict__ w_out, const float* __restrict__ w_gate,
            const float* __restrict__ w_up, const float* __restrict__ w_down,
            bf16* __restrict__ sdr_w_t, bf16* __restrict__ w_qkv_t,
            bf16* __restrict__ w_out_t, bf16* __restrict__ w_gate_t,
            bf16* __restrict__ w_up_t, bf16* __restrict__ w_down_t) {
  const int bid = blockIdx.x, t = threadIdx.x;
  if (bid < 512) {                       // convert region, fully coalesced
    const int base = bid * 8192 + t * 4;
    #pragma unroll
    for (int p = 0; p < 8; ++p) {
      const int i = base + p * 1024;
      float4 f = *(const float4*)(sdr + i);
      bf16x4 o;
      o[0] = (bf16)f.x; o[1] = (bf16)f.y; o[2] = (bf16)f.z; o[3] = (bf16)f.w;
      *(bf16x4*)(sdr_bf + i) = o;
    }
    return;
  }
  __shared__ float tile[64][65];
  const float* in; bf16* out; int K, N, Kpad, nnb, lb;
  if      (bid < 1024) { in = sdr_w;  out = sdr_w_t;  K = 2048; N = 1024; Kpad = 2048; nnb = 16; lb = bid - 512;  }
  else if (bid < 1792) { in = w_qkv;  out = w_qkv_t;  K = 1024; N = 3072; Kpad = 1024; nnb = 48; lb = bid - 1024; }
  else if (bid < 2048) { in = w_out;  out = w_out_t;  K = 1024; N = 1024; Kpad = 1024; nnb = 16; lb = bid - 1792; }
  else if (bid < 2752) { in = w_gate; out = w_gate_t; K = 1024; N = 2730; Kpad = 1024; nnb = 44; lb = bid - 2048; }
  else if (bid < 3456) { in = w_up;   out = w_up_t;   K = 1024; N = 2730; Kpad = 1024; nnb = 44; lb = bid - 2752; }
  else                 { in = w_down; out = w_down_t; K = 2730; N = 1024; Kpad = 2816; nnb = 16; lb = bid - 3456; }
  const int kb = (lb / nnb) * 64, nb = (lb % nnb) * 64;
  // read 64x64 fp32 (coalesced 256B rows), zero-pad
  #pragma unroll
  for (int i = 0; i < 4; ++i) {
    const int k = kb + (t >> 4) + i * 16;
    const int n = nb + (t & 15) * 4;
    float4 f = {0.f, 0.f, 0.f, 0.f};
    if (k < K) {
      if (n + 3 < N) f = *(const float4*)(in + (size_t)k * N + n);
      else {
        if (n + 0 < N) f.x = in[(size_t)k * N + n + 0];
        if (n + 1 < N) f.y = in[(size_t)k * N + n + 1];
        if (n + 2 < N) f.z = in[(size_t)k * N + n + 2];
        if (n + 3 < N) f.w = in[(size_t)k * N + n + 3];
      }
    }
    float* tr = &tile[(t >> 4) + i * 16][(t & 15) * 4];
    tr[0] = f.x; tr[1] = f.y; tr[2] = f.z; tr[3] = f.w;
  }
  __syncthreads();
  // write bf16x8 along k: 16B/thread, 128B segments
  #pragma unroll
  for (int i = 0; i < 2; ++i) {
    const int n = nb + (t >> 3) + i * 32;
    const int k = kb + (t & 7) * 8;
    bf16x8 o;
    #pragma unroll
    for (int j = 0; j < 8; ++j) o[j] = (bf16)tile[(t & 7) * 8 + j][(t >> 3) + i * 32];
    *(bf16x8*)(out + (size_t)n * Kpad + k) = o;
  }
}

// ---------------------------------------------------------------- layernorm
__global__ __launch_bounds__(256) void k_layernorm(const float* __restrict__ x,
    const float* __restrict__ gw, const float* __restrict__ bw, bf16* __restrict__ out) {
  const int row = blockIdx.x;           // 2048 rows, D=1024, 4 elems/thread
  const int t = threadIdx.x;
  const float* xr = x + (size_t)row * 1024;
  float4 f = *(const float4*)(xr + t * 4);
  float s  = f.x + f.y + f.z + f.w;
  float s2 = f.x * f.x + f.y * f.y + f.z * f.z + f.w * f.w;
  #pragma unroll
  for (int o = 32; o > 0; o >>= 1) { s += __shfl_down(s, o, 64); s2 += __shfl_down(s2, o, 64); }
  __shared__ float rA[4], rB[4];
  const int wid = t >> 6;
  if ((t & 63) == 0) { rA[wid] = s; rB[wid] = s2; }
  __syncthreads();
  s  = rA[0] + rA[1] + rA[2] + rA[3];
  s2 = rB[0] + rB[1] + rB[2] + rB[3];
  const float mu   = s * (1.f / 1024.f);
  const float var  = fmaxf(s2 * (1.f / 1024.f) - mu * mu, 0.f);
  const float rstd = rsqrtf(var + 1e-5f);
  float4 g4 = *(const float4*)(gw + t * 4);
  float4 b4 = *(const float4*)(bw + t * 4);
  bf16x4 o4;
  o4[0] = (bf16)((f.x - mu) * rstd * g4.x + b4.x);
  o4[1] = (bf16)((f.y - mu) * rstd * g4.y + b4.y);
  o4[2] = (bf16)((f.z - mu) * rstd * g4.z + b4.z);
  o4[3] = (bf16)((f.w - mu) * rstd * g4.w + b4.w);
  *(bf16x4*)(out + (size_t)row * 1024 + t * 4) = o4;
}

// ---------------------------------------------------------------- GEMMs (A[M][K] x Bt[N][K])
enum { EPI_BIAS = 1, EPI_BIAS_RES = 2, EPI_RES = 3, EPI_QKV = 5 };

template <int EPI>
DEV void gemm_epilogue(int rb, int cc, int Nn, const f32x4& a,
                       float* C, const float* bias, const float* res,
                       bf16* qp, bf16* kp, float* vbuf) {
  float bv = 0.f;
  if constexpr (EPI == EPI_BIAS || EPI == EPI_BIAS_RES || EPI == EPI_QKV) bv = bias[cc];
  #pragma unroll
  for (int v = 0; v < 4; ++v) {
    const int row = rb + v;
    float val = a[v] + bv;
    if constexpr (EPI == EPI_QKV) {
      const int bq = row >> 10, tt = row & 1023;
      if (cc < 1024) {        // q, pre-scaled by 1/sqrt(64)
        qp[(size_t)(bq * 16 + (cc >> 6)) * 65536 + (size_t)tt * 64 + (cc & 63)] = (bf16)(val * 0.125f);
      } else if (cc < 2048) { // k
        const int c2 = cc - 1024;
        kp[(size_t)(bq * 16 + (c2 >> 6)) * 65536 + (size_t)tt * 64 + (c2 & 63)] = (bf16)val;
      } else {                // v -> compact fp32 buffer [2048][1024]
        vbuf[(size_t)row * 1024 + (cc - 2048)] = val;
      }
    } else {
      const size_t idx = (size_t)row * Nn + cc;
      if constexpr (EPI == EPI_BIAS_RES || EPI == EPI_RES) val += res[idx];
      C[idx] = val;
    }
  }
}

// 128x128 tile, 4 waves (2x2 of 64x64), double-buffered LDS prefetch
template <int EPI>
__global__ __launch_bounds__(256, 2)
void k_gemm(const bf16* __restrict__ A, const bf16* __restrict__ Bt,
            float* __restrict__ C, const float* __restrict__ bias,
            const float* __restrict__ res, bf16* __restrict__ qp,
            bf16* __restrict__ kp, float* __restrict__ vbuf, int Nn, int Kk) {
  __shared__ __align__(16) bf16 As[2][128 * 64];
  __shared__ __align__(16) bf16 Bs[2][128 * 64];
  const int t = threadIdx.x;
  const int lane = t & 63, wid = t >> 6;
  const int wr = wid >> 1, wc = wid & 1;
  const int row0 = blockIdx.y * 128, col0 = blockIdx.x * 128;
  const int g  = t & 7;
  const int r0 = t >> 3;
  const int c16s = g ^ (r0 & 7);                      // pre-swizzled source group
  f32x4 acc[4][4] = {};

  auto stage = [&](int buf, int k0) {
    #pragma unroll
    for (int it = 0; it < 4; ++it) {
      int r = r0 + it * 32;
      gload_lds16(A + (size_t)(row0 + r) * Kk + k0 + c16s * 8, &As[buf][(it * 256 + wid * 64) * 8]);
    }
    #pragma unroll
    for (int it = 0; it < 4; ++it) {
      int r = r0 + it * 32;
      gload_lds16(Bt + (size_t)(col0 + r) * Kk + k0 + c16s * 8, &Bs[buf][(it * 256 + wid * 64) * 8]);
    }
  };

  stage(0, 0);
  __syncthreads();                                    // buf0 resident
  int cur = 0;
  for (int k0 = 0; k0 < Kk; k0 += 64) {
    if (k0 + 64 < Kk) stage(cur ^ 1, k0 + 64);        // prefetch next tile
    #pragma unroll
    for (int ks = 0; ks < 2; ++ks) {
      bf16x8 af[4], bfv[4];
      #pragma unroll
      for (int m = 0; m < 4; ++m) {
        int rr = wr * 64 + m * 16 + (lane & 15);
        int c16 = (ks * 4 + (lane >> 4)) ^ (rr & 7);
        af[m] = *(const bf16x8*)&As[cur][rr * 64 + c16 * 8];
      }
      #pragma unroll
      for (int n = 0; n < 4; ++n) {
        int rr = wc * 64 + n * 16 + (lane & 15);
        int c16 = (ks * 4 + (lane >> 4)) ^ (rr & 7);
        bfv[n] = *(const bf16x8*)&Bs[cur][rr * 64 + c16 * 8];
      }
      #pragma unroll
      for (int m = 0; m < 4; ++m)
        #pragma unroll
        for (int n = 0; n < 4; ++n)
          acc[m][n] = __builtin_amdgcn_mfma_f32_16x16x32_bf16(af[m], bfv[n], acc[m][n], 0, 0, 0);
    }
    __syncthreads();                                  // drains prefetch, guards reuse
    cur ^= 1;
  }
  #pragma unroll
  for (int m = 0; m < 4; ++m) {
    const int rb = row0 + wr * 64 + m * 16 + ((lane >> 4) << 2);
    #pragma unroll
    for (int n = 0; n < 4; ++n) {
      const int cc = col0 + wc * 64 + n * 16 + (lane & 15);
      gemm_epilogue<EPI>(rb, cc, Nn, acc[m][n], C, bias, res, qp, kp, vbuf);
    }
  }
}

// 128x64 tile, 4 waves stacked in M (wave = 32x64), double-buffered prefetch
template <int EPI>
__global__ __launch_bounds__(256, 2)
void k_gemm64(const bf16* __restrict__ A, const bf16* __restrict__ Bt,
              float* __restrict__ C, const float* __restrict__ bias,
              const float* __restrict__ res, int Nn, int Kk) {
  __shared__ __align__(16) bf16 As[2][128 * 64];
  __shared__ __align__(16) bf16 Bs[2][64 * 64];
  const int t = threadIdx.x;
  const int lane = t & 63, wid = t >> 6;
  const int row0 = blockIdx.y * 128, col0 = blockIdx.x * 64;
  const int g  = t & 7;
  const int r0 = t >> 3;
  const int c16s = g ^ (r0 & 7);
  f32x4 acc[2][4] = {};

  auto stage = [&](int buf, int k0) {
    #pragma unroll
    for (int it = 0; it < 4; ++it) {
      int r = r0 + it * 32;
      gload_lds16(A + (size_t)(row0 + r) * Kk + k0 + c16s * 8, &As[buf][(it * 256 + wid * 64) * 8]);
    }
    #pragma unroll
    for (int it = 0; it < 2; ++it) {
      int r = r0 + it * 32;
      gload_lds16(Bt + (size_t)(col0 + r) * Kk + k0 + c16s * 8, &Bs[buf][(it * 256 + wid * 64) * 8]);
    }
  };

  stage(0, 0);
  __syncthreads();
  int cur = 0;
  for (int k0 = 0; k0 < Kk; k0 += 64) {
    if (k0 + 64 < Kk) stage(cur ^ 1, k0 + 64);
    #pragma unroll
    for (int ks = 0; ks < 2; ++ks) {
      bf16x8 af[2], bfv[4];
      #pragma unroll
      for (int m = 0; m < 2; ++m) {
        int rr = wid * 32 + m * 16 + (lane & 15);
        int c16 = (ks * 4 + (lane >> 4)) ^ (rr & 7);
        af[m] = *(const bf16x8*)&As[cur][rr * 64 + c16 * 8];
      }
      #pragma unroll
      for (int n = 0; n < 4; ++n) {
        int rr = n * 16 + (lane & 15);
        int c16 = (ks * 4 + (lane >> 4)) ^ (rr & 7);
        bfv[n] = *(const bf16x8*)&Bs[cur][rr * 64 + c16 * 8];
      }
      #pragma unroll
      for (int m = 0; m < 2; ++m)
        #pragma unroll
        for (int n = 0; n < 4; ++n)
          acc[m][n] = __builtin_amdgcn_mfma_f32_16x16x32_bf16(af[m], bfv[n], acc[m][n], 0, 0, 0);
    }
    __syncthreads();
    cur ^= 1;
  }
  #pragma unroll
  for (int m = 0; m < 2; ++m) {
    const int rb = row0 + wid * 32 + m * 16 + ((lane >> 4) << 2);
    #pragma unroll
    for (int n = 0; n < 4; ++n) {
      const int cc = col0 + n * 16 + (lane & 15);
      gemm_epilogue<EPI>(rb, cc, Nn, acc[m][n], C, bias, res, nullptr, nullptr, nullptr);
    }
  }
}

// Fused SwiGLU GEMM: act = silu(A.Bg^T) * (A.Bu^T), A staged once, both accs live.
__global__ __launch_bounds__(256, 2)
void k_gemm_swiglu(const bf16* __restrict__ A, const bf16* __restrict__ Bg,
                   const bf16* __restrict__ Bu, bf16* __restrict__ act,
                   int Nn, int Kk) {
  __shared__ __align__(16) bf16 As[128 * 64];
  __shared__ __align__(16) bf16 Bgs[128 * 64];
  __shared__ __align__(16) bf16 Bus[128 * 64];
  const int t = threadIdx.x;
  const int lane = t & 63, wid = t >> 6;
  const int wr = wid >> 1, wc = wid & 1;
  const int row0 = blockIdx.y * 128, col0 = blockIdx.x * 128;
  const int g  = t & 7;
  const int r0 = t >> 3;
  const int c16s = g ^ (r0 & 7);
  f32x4 ag[4][4] = {}, au[4][4] = {};

  for (int k0 = 0; k0 < Kk; k0 += 64) {
    #pragma unroll
    for (int it = 0; it < 4; ++it) {
      int r = r0 + it * 32;
      gload_lds16(A + (size_t)(row0 + r) * Kk + k0 + c16s * 8, &As[(it * 256 + wid * 64) * 8]);
    }
    #pragma unroll
    for (int it = 0; it < 4; ++it) {
      int r = r0 + it * 32;
      gload_lds16(Bg + (size_t)(col0 + r) * Kk + k0 + c16s * 8, &Bgs[(it * 256 + wid * 64) * 8]);
    }
    #pragma unroll
    for (int it = 0; it < 4; ++it) {
      int r = r0 + it * 32;
      gload_lds16(Bu + (size_t)(col0 + r) * Kk + k0 + c16s * 8, &Bus[(it * 256 + wid * 64) * 8]);
    }
    __syncthreads();
    #pragma unroll
    for (int ks = 0; ks < 2; ++ks) {
      bf16x8 af[4], bg[4], bu[4];
      #pragma unroll
      for (int m = 0; m < 4; ++m) {
        int rr = wr * 64 + m * 16 + (lane & 15);
        int c16 = (ks * 4 + (lane >> 4)) ^ (rr & 7);
        af[m] = *(const bf16x8*)&As[rr * 64 + c16 * 8];
      }
      #pragma unroll
      for (int n = 0; n < 4; ++n) {
        int rr = wc * 64 + n * 16 + (lane & 15);
        int c16 = (ks * 4 + (lane >> 4)) ^ (rr & 7);
        bg[n] = *(const bf16x8*)&Bgs[rr * 64 + c16 * 8];
        bu[n] = *(const bf16x8*)&Bus[rr * 64 + c16 * 8];
      }
      #pragma unroll
      for (int m = 0; m < 4; ++m)
        #pragma unroll
        for (int n = 0; n < 4; ++n) {
          ag[m][n] = __builtin_amdgcn_mfma_f32_16x16x32_bf16(af[m], bg[n], ag[m][n], 0, 0, 0);
          au[m][n] = __builtin_amdgcn_mfma_f32_16x16x32_bf16(af[m], bu[n], au[m][n], 0, 0, 0);
        }
    }
    __syncthreads();
  }
  #pragma unroll
  for (int m = 0; m < 4; ++m) {
    const int rb = row0 + wr * 64 + m * 16 + ((lane >> 4) << 2);
    #pragma unroll
    for (int n = 0; n < 4; ++n) {
      const int cc = col0 + wc * 64 + n * 16 + (lane & 15);
      #pragma unroll
      for (int v = 0; v < 4; ++v) {
        float gt = ag[m][n][v], up = au[m][n][v];
        float sg = gt / (1.f + __expf(-gt));
        act[(size_t)(rb + v) * Nn + cc] = (bf16)(sg * up);
      }
    }
  }
}

// v fp32 [2048][1024] -> vT bf16 [32 bh][64 d][1024 t]
__global__ __launch_bounds__(256) void k_transpose_v(const float* __restrict__ vbuf,
                                                     bf16* __restrict__ vT) {
  __shared__ float tile[32][33];
  const int bh = blockIdx.z, b = bh >> 4, h = bh & 15;
  const int t0 = blockIdx.x * 32, d0 = blockIdx.y * 32;
  const int tx = threadIdx.x & 31, ty = threadIdx.x >> 5;
  for (int i = ty; i < 32; i += 8)
    tile[i][tx] = vbuf[(size_t)(b * 1024 + t0 + i) * 1024 + h * 64 + d0 + tx];
  __syncthreads();
  for (int i = ty; i < 32; i += 8)
    vT[(size_t)bh * 65536 + (size_t)(d0 + i) * 1024 + t0 + tx] = (bf16)tile[tx][i];
}

// ---------------------------------------------------------------- FHN flash attention
// R5 structure (proven 50us): 4 waves/block; block = (strip of 16 q-rows, bh).
// Wave w handles KV tiles j = w, w+4, ... with private online-softmax state +
// private P buffer (no intra-loop barriers). Final LDS merge. Heavy strips first.
#define FHN_DT 0.1f
#define FHN_A_ 0.7f

__global__ __launch_bounds__(256, 4)
void k_attn(const bf16* __restrict__ q, const bf16* __restrict__ k,
            const bf16* __restrict__ vT, bf16* __restrict__ ctx) {
  // union: [0,8KB) = 4x per-wave Ps (bf16 16x64); at merge:
  // [0,16KB) = comb f32[4][16][64], [16KB,16.5KB) = ml f32[4][16][2]
  __shared__ __align__(16) char smem[16896];
  const int bx = blockIdx.x;
  const int s  = 63 - (bx >> 5);              // heavy strips first
  const int bh = bx & 31;
  const int b = bh >> 4, hh = bh & 15;
  const int t = threadIdx.x;
  const int lane = t & 63, wid = t >> 6;
  const int l15 = lane & 15, g4 = lane >> 4;
  const int q0 = s * 16;
  bf16* Ps    = (bf16*)smem + wid * 1024;
  float* comb = (float*)smem;
  float* mlb  = (float*)(smem + 16384);
  const bf16* qb = q  + (size_t)bh * 65536;
  const bf16* kb = k  + (size_t)bh * 65536;
  const bf16* vb = vT + (size_t)bh * 65536;
  const float wden = 1.0f / (1.0f + FHN_DT * 0.8f / 12.5f);
  const float dtau = FHN_DT / 12.5f;

  // Q fragments (A-layout: row=l15, k=g4*8+e per 32-chunk), q pre-scaled
  bf16x8 qf[2];
  #pragma unroll
  for (int ks = 0; ks < 2; ++ks)
    qf[ks] = *(const bf16x8*)(qb + (size_t)(q0 + l15) * 64 + ks * 32 + g4 * 8);

  f32x4 o[4] = {};
  f32x4 mrow = {-1e30f, -1e30f, -1e30f, -1e30f};
  f32x4 ssum = {0.f, 0.f, 0.f, 0.f};
  const int jn = (q0 >> 6) + 1;

  for (int j = wid; j < jn; j += 4) {
    const int kv0 = j * 64;
    // S = Q . K^T ; B-frag from K[kv][d] rows (16B contiguous in d)
    f32x4 sc[4] = {};
    #pragma unroll
    for (int ks = 0; ks < 2; ++ks)
      #pragma unroll
      for (int n = 0; n < 4; ++n) {
        bf16x8 kf = *(const bf16x8*)(kb + (size_t)(kv0 + n * 16 + l15) * 64 + ks * 32 + g4 * 8);
        sc[n] = __builtin_amdgcn_mfma_f32_16x16x32_bf16(qf[ks], kf, sc[n], 0, 0, 0);
      }
    // FHN IMEX + threshold + causal mask (only tile jn-1 straddles the diagonal)
    const int rbase = q0 + (g4 << 2);
    #pragma unroll
    for (int n = 0; n < 4; ++n)
      #pragma unroll
      for (int v = 0; v < 4; ++v) {
        float sv = sc[n][v];
        float vv = sv, ww = 0.f;
        #pragma unroll
        for (int st = 0; st < 4; ++st) {
          vv = vv + FHN_DT * (vv - vv * vv * vv * (1.f / 3.f) - ww + sv);
          ww = (ww + dtau * (vv + FHN_A_)) * wden;
        }
        float lg = vv - 0.5f;
        if (j == jn - 1) {
          int kvi = kv0 + n * 16 + l15;
          if (kvi > rbase + v) lg = -1e9f;
        }
        sc[n][v] = lg;
      }
    // online softmax (rows live in 16-lane groups)
    f32x4 mnew, scl;
    #pragma unroll
    for (int v = 0; v < 4; ++v) {
      float m0 = fmaxf(fmaxf(sc[0][v], sc[1][v]), fmaxf(sc[2][v], sc[3][v]));
      #pragma unroll
      for (int msk = 1; msk < 16; msk <<= 1) m0 = fmaxf(m0, __shfl_xor(m0, msk, 64));
      mnew[v] = fmaxf(mrow[v], m0);
      scl[v] = __expf(mrow[v] - mnew[v]);
    }
    #pragma unroll
    for (int v = 0; v < 4; ++v) {
      float rs = 0.f;
      #pragma unroll
      for (int n = 0; n < 4; ++n) {
        float p = __expf(sc[n][v] - mnew[v]);
        sc[n][v] = p;
        rs += p;
      }
      #pragma unroll
      for (int msk = 1; msk < 16; msk <<= 1) rs += __shfl_xor(rs, msk, 64);
      ssum[v] = ssum[v] * scl[v] + rs;
      mrow[v] = mnew[v];
    }
    #pragma unroll
    for (int n = 0; n < 4; ++n) o[n] *= scl;
    // P -> bf16 -> per-wave swizzled LDS (wave-local RAW, compiler inserts waits)
    #pragma unroll
    for (int n = 0; n < 4; ++n)
      #pragma unroll
      for (int v = 0; v < 4; ++v) {
        int rr = (g4 << 2) + v;
        int c = n * 16 + l15;
        int c16 = (c >> 3) ^ (rr & 7);
        Ps[rr * 64 + c16 * 8 + (c & 7)] = (bf16)sc[n][v];
      }
    // O += P . V   (B-frag from vT[d][t], 16B contiguous in t)
    #pragma unroll
    for (int ks = 0; ks < 2; ++ks) {
      int c16 = (ks * 4 + g4) ^ (l15 & 7);
      bf16x8 pa = *(const bf16x8*)&Ps[l15 * 64 + c16 * 8];
      #pragma unroll
      for (int n = 0; n < 4; ++n) {
        bf16x8 vf = *(const bf16x8*)(vb + (size_t)(n * 16 + l15) * 1024 + kv0 + ks * 32 + g4 * 8);
        o[n] = __builtin_amdgcn_mfma_f32_16x16x32_bf16(pa, vf, o[n], 0, 0, 0);
      }
    }
  }
  __syncthreads();                 // all Ps reads done -> comb may overwrite
  // write partials (empty waves contribute m=-1e30, l=0, o=0 -> factor 0)
  #pragma unroll
  for (int n = 0; n < 4; ++n)
    #pragma unroll
    for (int v = 0; v < 4; ++v)
      comb[(wid * 16 + (g4 << 2) + v) * 64 + n * 16 + l15] = o[n][v];
  if (l15 == 0) {
    #pragma unroll
    for (int v = 0; v < 4; ++v) {
      mlb[(wid * 16 + (g4 << 2) + v) * 2 + 0] = mrow[v];
      mlb[(wid * 16 + (g4 << 2) + v) * 2 + 1] = ssum[v];
    }
  }
  __syncthreads();
  // merge: thread t handles (row = t>>4, 4 d-values at dseg = t&15)
  {
    const int row = t >> 4, dseg = t & 15;
    float m = mlb[row * 2];
    #pragma unroll
    for (int w = 1; w < 4; ++w) m = fmaxf(m, mlb[(w * 16 + row) * 2]);
    float L = 0.f;
    f32x4 a = {0.f, 0.f, 0.f, 0.f};
    #pragma unroll
    for (int w = 0; w < 4; ++w) {
      float f = __expf(mlb[(w * 16 + row) * 2] - m);
      L += f * mlb[(w * 16 + row) * 2 + 1];
      f32x4 c = *(const f32x4*)&comb[(w * 16 + row) * 64 + dseg * 4];
      a += c * f;
    }
    const float inv = 1.f / L;
    bf16x4 o4;
    o4[0] = (bf16)(a[0] * inv); o4[1] = (bf16)(a[1] * inv);
    o4[2] = (bf16)(a[2] * inv); o4[3] = (bf16)(a[3] * inv);
    *(bf16x4*)&ctx[(size_t)(b * 1024 + q0 + row) * 1024 + hh * 64 + dseg * 4] = o4;
  }
}

// ---------------------------------------------------------------- launch
extern "C" void kernel_launch(void* const* d_in, const int* in_sizes, int n_in,
                              void* d_out, int out_size, void* d_ws, size_t ws_size,
                              hipStream_t stream) {
  (void)in_sizes; (void)n_in; (void)out_size; (void)ws_size;
  const float* sdr    = (const float*)d_in[0];
  const float* sdr_w  = (const float*)d_in[1];
  const float* sdr_b  = (const float*)d_in[2];
  const float* w_qkv  = (const float*)d_in[3];
  const float* b_qkv  = (const float*)d_in[4];
  const float* w_out  = (const float*)d_in[5];
  const float* b_out  = (const float*)d_in[6];
  const float* ln1_g  = (const float*)d_in[7];
  const float* ln1_b  = (const float*)d_in[8];
  const float* ln2_g  = (const float*)d_in[9];
  const float* ln2_b  = (const float*)d_in[10];
  const float* w_gate = (const float*)d_in[11];
  const float* w_up   = (const float*)d_in[12];
  const float* w_down = (const float*)d_in[13];
  float* out = (float*)d_out;

  char* wsb = (char*)d_ws;
  size_t off = 0;
  auto alloc = [&](size_t bytes) -> void* {
    void* p = (void*)(wsb + off);
    off += (bytes + 255) & ~(size_t)255;
    return p;
  };
  bf16* sdr_w_t  = (bf16*)alloc(1024ull * 2048 * 2);
  bf16* w_qkv_t  = (bf16*)alloc(3072ull * 1024 * 2);
  bf16* w_out_t  = (bf16*)alloc(1024ull * 1024 * 2);
  bf16* w_gate_t = (bf16*)alloc(2816ull * 1024 * 2);
  bf16* w_up_t   = (bf16*)alloc(2816ull * 1024 * 2);
  bf16* w_down_t = (bf16*)alloc(1024ull * 2816 * 2);
  bf16* big_bf   = (bf16*)alloc(2048ull * 2816 * 2);  // sdr_bf16 then act (time-shared)
  bf16* sdr_bf   = big_bf;
  bf16* act      = big_bf;
  float* x       = (float*)alloc(2048ull * 1024 * 4);
  bf16*  h       = (bf16*)alloc(2048ull * 1024 * 2);  // h1 then h2 (time-shared)
  float* vbuf    = (float*)alloc(2048ull * 1024 * 4);
  bf16*  qb      = (bf16*)alloc(32ull * 1024 * 64 * 2);
  bf16*  kb      = (bf16*)alloc(32ull * 1024 * 64 * 2);
  bf16*  vT      = (bf16*)alloc(32ull * 1024 * 64 * 2);
  bf16*  ctx     = (bf16*)alloc(2048ull * 1024 * 2);
  float* x2      = (float*)alloc(2048ull * 1024 * 4);

  // fused prep: sdr convert + all 6 weight transposes (one launch)
  k_prep<<<4160, 256, 0, stream>>>(sdr, sdr_bf, sdr_w, w_qkv, w_out, w_gate,
                                   w_up, w_down, sdr_w_t, w_qkv_t, w_out_t,
                                   w_gate_t, w_up_t, w_down_t);

  // x = sdr @ sdr_w + sdr_b
  k_gemm64<EPI_BIAS><<<dim3(16, 16), 256, 0, stream>>>(sdr_bf, sdr_w_t, x, sdr_b, nullptr, 1024, 2048);
  k_layernorm<<<2048, 256, 0, stream>>>(x, ln1_g, ln1_b, h);
  // qkv GEMM with fused split: q,k bf16 [bh][t][d] (q pre-scaled), v fp32 compact
  k_gemm<EPI_QKV><<<dim3(24, 16), 256, 0, stream>>>(h, w_qkv_t, nullptr, b_qkv, nullptr, qb, kb, vbuf, 3072, 1024);
  k_transpose_v<<<dim3(32, 2, 32), 256, 0, stream>>>(vbuf, vT);
  // FHN flash attention (64 strips x 32 bh, heavy-first, 4-wave KV split)
  k_attn<<<2048, 256, 0, stream>>>(qb, kb, vT, ctx);
  // x2 = x + ctx @ w_out + b_out
  k_gemm64<EPI_BIAS_RES><<<dim3(16, 16), 256, 0, stream>>>(ctx, w_out_t, x2, b_out, x, 1024, 1024);
  k_layernorm<<<2048, 256, 0, stream>>>(x2, ln2_g, ln2_b, h);
  // act = silu(h2 @ w_gate) * (h2 @ w_up)  (fused, A staged once)
  k_gemm_swiglu<<<dim3(22, 16), 256, 0, stream>>>(h, w_gate_t, w_up_t, act, 2816, 1024);
  // out = x2 + act @ w_down
  k_gemm64<EPI_RES><<<dim3(16, 16), 256, 0, stream>>>(act, w_down_t, out, nullptr, x2, 1024, 2816);
}

// Round 8
// 304.987 us; speedup vs baseline: 1.2007x; 1.0759x over previous
//
#include <hip/hip_runtime.h>
#include <hip/hip_bf16.h>
#include <math.h>

// NeuroManifoldBlock: sdr_proj -> LN1 -> FHN-causal-attn -> +res -> LN2 -> SwiGLU -> +res
// B=2 T=1024 SDR=2048 D=1024 H=16 DH=64 FFN_H=2730 (padded 2816)
// R8: (a) attn: FIXED-SHIFT softmax (M=4.0). FHN cubic damping bounds logits
//     (~±3), softmax is shift-invariant -> exact. Removes ALL in-loop
//     reductions (32 shfl/tile), max tracking, O-rescale; ssum reduced once.
//     Merge becomes plain sums.
//     (b) split-K x2 for the three N=1024 GEMMs (grid 256 -> 512 blocks =
//     2/CU; restores m114 sibling-wave overlap of the staging drain).
//     Reductions fused into LN kernels (read partials+bias+res, write h + x).
//     w_down reduced by tiny k_final (out = x2 + p0 + p1).

typedef __bf16 bf16;
typedef __bf16 bf16x4 __attribute__((ext_vector_type(4)));
typedef __bf16 bf16x8 __attribute__((ext_vector_type(8)));
typedef float  f32x4  __attribute__((ext_vector_type(4)));

#define DEV __device__ __forceinline__

DEV void gload_lds16(const void* g, void* l) {
  __builtin_amdgcn_global_load_lds(
      (const __attribute__((address_space(1))) void*)g,
      (__attribute__((address_space(3))) void*)l, 16, 0, 0);
}

// ---------------------------------------------------------------- fused prep
__global__ __launch_bounds__(256)
void k_prep(const float* __restrict__ sdr, bf16* __restrict__ sdr_bf,
            const float* __restrict__ sdr_w, const float* __restrict__ w_qkv,
            const float* __restrict__ w_out, const float* __restrict__ w_gate,
            const float* __restrict__ w_up, const float* __restrict__ w_down,
            bf16* __restrict__ sdr_w_t, bf16* __restrict__ w_qkv_t,
            bf16* __restrict__ w_out_t, bf16* __restrict__ w_gate_t,
            bf16* __restrict__ w_up_t, bf16* __restrict__ w_down_t) {
  const int bid = blockIdx.x, t = threadIdx.x;
  if (bid < 512) {                       // sdr fp32->bf16, fully coalesced
    const int base = bid * 8192 + t * 4;
    #pragma unroll
    for (int p = 0; p < 8; ++p) {
      const int i = base + p * 1024;
      float4 f = *(const float4*)(sdr + i);
      bf16x4 o;
      o[0] = (bf16)f.x; o[1] = (bf16)f.y; o[2] = (bf16)f.z; o[3] = (bf16)f.w;
      *(bf16x4*)(sdr_bf + i) = o;
    }
    return;
  }
  __shared__ float tile[64][65];
  const float* in; bf16* out; int K, N, Kpad, nnb, lb;
  if      (bid < 1024) { in = sdr_w;  out = sdr_w_t;  K = 2048; N = 1024; Kpad = 2048; nnb = 16; lb = bid - 512;  }
  else if (bid < 1792) { in = w_qkv;  out = w_qkv_t;  K = 1024; N = 3072; Kpad = 1024; nnb = 48; lb = bid - 1024; }
  else if (bid < 2048) { in = w_out;  out = w_out_t;  K = 1024; N = 1024; Kpad = 1024; nnb = 16; lb = bid - 1792; }
  else if (bid < 2752) { in = w_gate; out = w_gate_t; K = 1024; N = 2730; Kpad = 1024; nnb = 44; lb = bid - 2048; }
  else if (bid < 3456) { in = w_up;   out = w_up_t;   K = 1024; N = 2730; Kpad = 1024; nnb = 44; lb = bid - 2752; }
  else                 { in = w_down; out = w_down_t; K = 2730; N = 1024; Kpad = 2816; nnb = 16; lb = bid - 3456; }
  const int kb = (lb / nnb) * 64, nb = (lb % nnb) * 64;
  #pragma unroll
  for (int i = 0; i < 4; ++i) {
    const int k = kb + (t >> 4) + i * 16;
    const int n = nb + (t & 15) * 4;
    float4 f = {0.f, 0.f, 0.f, 0.f};
    if (k < K) {
      if (n + 3 < N) f = *(const float4*)(in + (size_t)k * N + n);
      else {
        if (n + 0 < N) f.x = in[(size_t)k * N + n + 0];
        if (n + 1 < N) f.y = in[(size_t)k * N + n + 1];
        if (n + 2 < N) f.z = in[(size_t)k * N + n + 2];
        if (n + 3 < N) f.w = in[(size_t)k * N + n + 3];
      }
    }
    float* tr = &tile[(t >> 4) + i * 16][(t & 15) * 4];
    tr[0] = f.x; tr[1] = f.y; tr[2] = f.z; tr[3] = f.w;
  }
  __syncthreads();
  #pragma unroll
  for (int i = 0; i < 2; ++i) {
    const int n = nb + (t >> 3) + i * 32;
    const int k = kb + (t & 7) * 8;
    bf16x8 o;
    #pragma unroll
    for (int j = 0; j < 8; ++j) o[j] = (bf16)tile[(t & 7) * 8 + j][(t >> 3) + i * 32];
    *(bf16x8*)(out + (size_t)n * Kpad + k) = o;
  }
}

// ---------------------------------------------------------------- layernorm (fused split-K reduce)
// val = p0 + p1 + bias (+ res). Writes xout fp32 (residual source) + h bf16 (LN'd).
__global__ __launch_bounds__(256) void k_layernorm2(
    const float* __restrict__ p0, const float* __restrict__ p1,
    const float* __restrict__ res, const float* __restrict__ bias,
    const float* __restrict__ gw, const float* __restrict__ bw,
    bf16* __restrict__ h, float* __restrict__ xout) {
  const int row = blockIdx.x, t = threadIdx.x;
  const size_t base = (size_t)row * 1024 + t * 4;
  float4 a = *(const float4*)(p0 + base);
  float4 b = *(const float4*)(p1 + base);
  float4 bv = *(const float4*)(bias + t * 4);
  float4 f;
  f.x = a.x + b.x + bv.x; f.y = a.y + b.y + bv.y;
  f.z = a.z + b.z + bv.z; f.w = a.w + b.w + bv.w;
  if (res) {
    float4 r = *(const float4*)(res + base);
    f.x += r.x; f.y += r.y; f.z += r.z; f.w += r.w;
  }
  *(float4*)(xout + base) = f;
  float s  = f.x + f.y + f.z + f.w;
  float s2 = f.x * f.x + f.y * f.y + f.z * f.z + f.w * f.w;
  #pragma unroll
  for (int o = 32; o > 0; o >>= 1) { s += __shfl_down(s, o, 64); s2 += __shfl_down(s2, o, 64); }
  __shared__ float rA[4], rB[4];
  const int wid = t >> 6;
  if ((t & 63) == 0) { rA[wid] = s; rB[wid] = s2; }
  __syncthreads();
  s  = rA[0] + rA[1] + rA[2] + rA[3];
  s2 = rB[0] + rB[1] + rB[2] + rB[3];
  const float mu   = s * (1.f / 1024.f);
  const float var  = fmaxf(s2 * (1.f / 1024.f) - mu * mu, 0.f);
  const float rstd = rsqrtf(var + 1e-5f);
  float4 g4 = *(const float4*)(gw + t * 4);
  float4 b4 = *(const float4*)(bw + t * 4);
  bf16x4 o4;
  o4[0] = (bf16)((f.x - mu) * rstd * g4.x + b4.x);
  o4[1] = (bf16)((f.y - mu) * rstd * g4.y + b4.y);
  o4[2] = (bf16)((f.z - mu) * rstd * g4.z + b4.z);
  o4[3] = (bf16)((f.w - mu) * rstd * g4.w + b4.w);
  *(bf16x4*)(h + base) = o4;
}

// final: out = x2 + p0 + p1
__global__ __launch_bounds__(256) void k_final(const float* __restrict__ x2,
    const float* __restrict__ p0, const float* __restrict__ p1,
    float* __restrict__ out) {
  const size_t i = ((size_t)blockIdx.x * 256 + threadIdx.x) * 4;
  float4 a = *(const float4*)(x2 + i);
  float4 b = *(const float4*)(p0 + i);
  float4 c = *(const float4*)(p1 + i);
  float4 o;
  o.x = a.x + b.x + c.x; o.y = a.y + b.y + c.y;
  o.z = a.z + b.z + c.z; o.w = a.w + b.w + c.w;
  *(float4*)(out + i) = o;
}

// ---------------------------------------------------------------- GEMMs (A[M][K] x Bt[N][K])
enum { EPI_QKV = 5 };

// 128x128 tile, 4 waves (2x2 of 64x64), dbuf prefetch (qkv only)
template <int EPI>
__global__ __launch_bounds__(256, 2)
void k_gemm(const bf16* __restrict__ A, const bf16* __restrict__ Bt,
            const float* __restrict__ bias, bf16* __restrict__ qp,
            bf16* __restrict__ kp, float* __restrict__ vbuf, int Nn, int Kk) {
  __shared__ __align__(16) bf16 As[2][128 * 64];
  __shared__ __align__(16) bf16 Bs[2][128 * 64];
  const int t = threadIdx.x;
  const int lane = t & 63, wid = t >> 6;
  const int wr = wid >> 1, wc = wid & 1;
  const int row0 = blockIdx.y * 128, col0 = blockIdx.x * 128;
  const int g  = t & 7;
  const int r0 = t >> 3;
  const int c16s = g ^ (r0 & 7);
  f32x4 acc[4][4] = {};

  auto stage = [&](int buf, int k0) {
    #pragma unroll
    for (int it = 0; it < 4; ++it) {
      int r = r0 + it * 32;
      gload_lds16(A + (size_t)(row0 + r) * Kk + k0 + c16s * 8, &As[buf][(it * 256 + wid * 64) * 8]);
    }
    #pragma unroll
    for (int it = 0; it < 4; ++it) {
      int r = r0 + it * 32;
      gload_lds16(Bt + (size_t)(col0 + r) * Kk + k0 + c16s * 8, &Bs[buf][(it * 256 + wid * 64) * 8]);
    }
  };

  stage(0, 0);
  __syncthreads();
  int cur = 0;
  for (int k0 = 0; k0 < Kk; k0 += 64) {
    if (k0 + 64 < Kk) stage(cur ^ 1, k0 + 64);
    #pragma unroll
    for (int ks = 0; ks < 2; ++ks) {
      bf16x8 af[4], bfv[4];
      #pragma unroll
      for (int m = 0; m < 4; ++m) {
        int rr = wr * 64 + m * 16 + (lane & 15);
        int c16 = (ks * 4 + (lane >> 4)) ^ (rr & 7);
        af[m] = *(const bf16x8*)&As[cur][rr * 64 + c16 * 8];
      }
      #pragma unroll
      for (int n = 0; n < 4; ++n) {
        int rr = wc * 64 + n * 16 + (lane & 15);
        int c16 = (ks * 4 + (lane >> 4)) ^ (rr & 7);
        bfv[n] = *(const bf16x8*)&Bs[cur][rr * 64 + c16 * 8];
      }
      #pragma unroll
      for (int m = 0; m < 4; ++m)
        #pragma unroll
        for (int n = 0; n < 4; ++n)
          acc[m][n] = __builtin_amdgcn_mfma_f32_16x16x32_bf16(af[m], bfv[n], acc[m][n], 0, 0, 0);
    }
    __syncthreads();
    cur ^= 1;
  }
  #pragma unroll
  for (int m = 0; m < 4; ++m) {
    const int rb = row0 + wr * 64 + m * 16 + ((lane >> 4) << 2);
    #pragma unroll
    for (int n = 0; n < 4; ++n) {
      const int cc = col0 + wc * 64 + n * 16 + (lane & 15);
      const float bv = bias[cc];
      #pragma unroll
      for (int v = 0; v < 4; ++v) {
        const int row = rb + v;
        float val = acc[m][n][v] + bv;
        const int bq = row >> 10, tt = row & 1023;
        if (cc < 1024) {
          qp[(size_t)(bq * 16 + (cc >> 6)) * 65536 + (size_t)tt * 64 + (cc & 63)] = (bf16)(val * 0.125f);
        } else if (cc < 2048) {
          const int c2 = cc - 1024;
          kp[(size_t)(bq * 16 + (c2 >> 6)) * 65536 + (size_t)tt * 64 + (c2 & 63)] = (bf16)val;
        } else {
          vbuf[(size_t)row * 1024 + (cc - 2048)] = val;
        }
      }
    }
  }
}

// 128x64 tile, 4 waves stacked in M, dbuf prefetch, SPLIT-K x2 (blockIdx.z),
// plain partial-fp32 epilogue: C + z*2048*Nn.
__global__ __launch_bounds__(256, 2)
void k_gemm64(const bf16* __restrict__ A, const bf16* __restrict__ Bt,
              float* __restrict__ C, int Nn, int Kk) {
  __shared__ __align__(16) bf16 As[2][128 * 64];
  __shared__ __align__(16) bf16 Bs[2][64 * 64];
  const int t = threadIdx.x;
  const int lane = t & 63, wid = t >> 6;
  const int row0 = blockIdx.y * 128, col0 = blockIdx.x * 64;
  const int z = blockIdx.z;
  const int KH = Kk >> 1, kb = z * KH;
  float* Cp = C + (size_t)z * 2048 * Nn;
  const int g  = t & 7;
  const int r0 = t >> 3;
  const int c16s = g ^ (r0 & 7);
  f32x4 acc[2][4] = {};

  auto stage = [&](int buf, int k0) {
    #pragma unroll
    for (int it = 0; it < 4; ++it) {
      int r = r0 + it * 32;
      gload_lds16(A + (size_t)(row0 + r) * Kk + kb + k0 + c16s * 8, &As[buf][(it * 256 + wid * 64) * 8]);
    }
    #pragma unroll
    for (int it = 0; it < 2; ++it) {
      int r = r0 + it * 32;
      gload_lds16(Bt + (size_t)(col0 + r) * Kk + kb + k0 + c16s * 8, &Bs[buf][(it * 256 + wid * 64) * 8]);
    }
  };

  stage(0, 0);
  __syncthreads();
  int cur = 0;
  for (int k0 = 0; k0 < KH; k0 += 64) {
    if (k0 + 64 < KH) stage(cur ^ 1, k0 + 64);
    #pragma unroll
    for (int ks = 0; ks < 2; ++ks) {
      bf16x8 af[2], bfv[4];
      #pragma unroll
      for (int m = 0; m < 2; ++m) {
        int rr = wid * 32 + m * 16 + (lane & 15);
        int c16 = (ks * 4 + (lane >> 4)) ^ (rr & 7);
        af[m] = *(const bf16x8*)&As[cur][rr * 64 + c16 * 8];
      }
      #pragma unroll
      for (int n = 0; n < 4; ++n) {
        int rr = n * 16 + (lane & 15);
        int c16 = (ks * 4 + (lane >> 4)) ^ (rr & 7);
        bfv[n] = *(const bf16x8*)&Bs[cur][rr * 64 + c16 * 8];
      }
      #pragma unroll
      for (int m = 0; m < 2; ++m)
        #pragma unroll
        for (int n = 0; n < 4; ++n)
          acc[m][n] = __builtin_amdgcn_mfma_f32_16x16x32_bf16(af[m], bfv[n], acc[m][n], 0, 0, 0);
    }
    __syncthreads();
    cur ^= 1;
  }
  #pragma unroll
  for (int m = 0; m < 2; ++m) {
    const int rb = row0 + wid * 32 + m * 16 + ((lane >> 4) << 2);
    #pragma unroll
    for (int n = 0; n < 4; ++n) {
      const int cc = col0 + n * 16 + (lane & 15);
      #pragma unroll
      for (int v = 0; v < 4; ++v)
        Cp[(size_t)(rb + v) * Nn + cc] = acc[m][n][v];
    }
  }
}

// Fused SwiGLU GEMM (unchanged)
__global__ __launch_bounds__(256, 2)
void k_gemm_swiglu(const bf16* __restrict__ A, const bf16* __restrict__ Bg,
                   const bf16* __restrict__ Bu, bf16* __restrict__ act,
                   int Nn, int Kk) {
  __shared__ __align__(16) bf16 As[128 * 64];
  __shared__ __align__(16) bf16 Bgs[128 * 64];
  __shared__ __align__(16) bf16 Bus[128 * 64];
  const int t = threadIdx.x;
  const int lane = t & 63, wid = t >> 6;
  const int wr = wid >> 1, wc = wid & 1;
  const int row0 = blockIdx.y * 128, col0 = blockIdx.x * 128;
  const int g  = t & 7;
  const int r0 = t >> 3;
  const int c16s = g ^ (r0 & 7);
  f32x4 ag[4][4] = {}, au[4][4] = {};

  for (int k0 = 0; k0 < Kk; k0 += 64) {
    #pragma unroll
    for (int it = 0; it < 4; ++it) {
      int r = r0 + it * 32;
      gload_lds16(A + (size_t)(row0 + r) * Kk + k0 + c16s * 8, &As[(it * 256 + wid * 64) * 8]);
    }
    #pragma unroll
    for (int it = 0; it < 4; ++it) {
      int r = r0 + it * 32;
      gload_lds16(Bg + (size_t)(col0 + r) * Kk + k0 + c16s * 8, &Bgs[(it * 256 + wid * 64) * 8]);
    }
    #pragma unroll
    for (int it = 0; it < 4; ++it) {
      int r = r0 + it * 32;
      gload_lds16(Bu + (size_t)(col0 + r) * Kk + k0 + c16s * 8, &Bus[(it * 256 + wid * 64) * 8]);
    }
    __syncthreads();
    #pragma unroll
    for (int ks = 0; ks < 2; ++ks) {
      bf16x8 af[4], bg[4], bu[4];
      #pragma unroll
      for (int m = 0; m < 4; ++m) {
        int rr = wr * 64 + m * 16 + (lane & 15);
        int c16 = (ks * 4 + (lane >> 4)) ^ (rr & 7);
        af[m] = *(const bf16x8*)&As[rr * 64 + c16 * 8];
      }
      #pragma unroll
      for (int n = 0; n < 4; ++n) {
        int rr = wc * 64 + n * 16 + (lane & 15);
        int c16 = (ks * 4 + (lane >> 4)) ^ (rr & 7);
        bg[n] = *(const bf16x8*)&Bgs[rr * 64 + c16 * 8];
        bu[n] = *(const bf16x8*)&Bus[rr * 64 + c16 * 8];
      }
      #pragma unroll
      for (int m = 0; m < 4; ++m)
        #pragma unroll
        for (int n = 0; n < 4; ++n) {
          ag[m][n] = __builtin_amdgcn_mfma_f32_16x16x32_bf16(af[m], bg[n], ag[m][n], 0, 0, 0);
          au[m][n] = __builtin_amdgcn_mfma_f32_16x16x32_bf16(af[m], bu[n], au[m][n], 0, 0, 0);
        }
    }
    __syncthreads();
  }
  #pragma unroll
  for (int m = 0; m < 4; ++m) {
    const int rb = row0 + wr * 64 + m * 16 + ((lane >> 4) << 2);
    #pragma unroll
    for (int n = 0; n < 4; ++n) {
      const int cc = col0 + wc * 64 + n * 16 + (lane & 15);
      #pragma unroll
      for (int v = 0; v < 4; ++v) {
        float gt = ag[m][n][v], up = au[m][n][v];
        float sg = gt / (1.f + __expf(-gt));
        act[(size_t)(rb + v) * Nn + cc] = (bf16)(sg * up);
      }
    }
  }
}

// v fp32 [2048][1024] -> vT bf16 [32 bh][64 d][1024 t]
__global__ __launch_bounds__(256) void k_transpose_v(const float* __restrict__ vbuf,
                                                     bf16* __restrict__ vT) {
  __shared__ float tile[32][33];
  const int bh = blockIdx.z, b = bh >> 4, h = bh & 15;
  const int t0 = blockIdx.x * 32, d0 = blockIdx.y * 32;
  const int tx = threadIdx.x & 31, ty = threadIdx.x >> 5;
  for (int i = ty; i < 32; i += 8)
    tile[i][tx] = vbuf[(size_t)(b * 1024 + t0 + i) * 1024 + h * 64 + d0 + tx];
  __syncthreads();
  for (int i = ty; i < 32; i += 8)
    vT[(size_t)bh * 65536 + (size_t)(d0 + i) * 1024 + t0 + tx] = (bf16)tile[tx][i];
}

// ---------------------------------------------------------------- FHN flash attention
// R5 structure + FIXED-SHIFT softmax: p = exp(logit - 4). FHN's cubic damping
// bounds logits (~±3 for any plausible score), softmax is shift-invariant, so
// result is exact; removes max tracking, O-rescale, and all in-loop shuffles.
// ssum accumulated per-lane, reduced once per strip. Merge = plain sums.
#define FHN_DT 0.1f
#define FHN_A_ 0.7f

__global__ __launch_bounds__(256, 4)
void k_attn(const bf16* __restrict__ q, const bf16* __restrict__ k,
            const bf16* __restrict__ vT, bf16* __restrict__ ctx) {
  // union: [0,8KB) = 4x per-wave Ps (bf16 16x64); at merge:
  // [0,16KB) = comb f32[4][16][64], [16KB,+256) = lsum f32[4][16]
  __shared__ __align__(16) char smem[16896];
  const int bx = blockIdx.x;
  const int s  = 63 - (bx >> 5);              // heavy strips first
  const int bh = bx & 31;
  const int b = bh >> 4, hh = bh & 15;
  const int t = threadIdx.x;
  const int lane = t & 63, wid = t >> 6;
  const int l15 = lane & 15, g4 = lane >> 4;
  const int q0 = s * 16;
  bf16* Ps    = (bf16*)smem + wid * 1024;
  float* comb = (float*)smem;
  float* lsum = (float*)(smem + 16384);
  const bf16* qb = q  + (size_t)bh * 65536;
  const bf16* kb = k  + (size_t)bh * 65536;
  const bf16* vb = vT + (size_t)bh * 65536;
  const float wden = 1.0f / (1.0f + FHN_DT * 0.8f / 12.5f);
  const float dtau = FHN_DT / 12.5f;

  bf16x8 qf[2];
  #pragma unroll
  for (int ks = 0; ks < 2; ++ks)
    qf[ks] = *(const bf16x8*)(qb + (size_t)(q0 + l15) * 64 + ks * 32 + g4 * 8);

  f32x4 o[4] = {};
  f32x4 ssum = {0.f, 0.f, 0.f, 0.f};
  const int jn = (q0 >> 6) + 1;

  for (int j = wid; j < jn; j += 4) {
    const int kv0 = j * 64;
    // S = Q . K^T
    f32x4 sc[4] = {};
    #pragma unroll
    for (int ks = 0; ks < 2; ++ks)
      #pragma unroll
      for (int n = 0; n < 4; ++n) {
        bf16x8 kf = *(const bf16x8*)(kb + (size_t)(kv0 + n * 16 + l15) * 64 + ks * 32 + g4 * 8);
        sc[n] = __builtin_amdgcn_mfma_f32_16x16x32_bf16(qf[ks], kf, sc[n], 0, 0, 0);
      }
    // FHN IMEX + threshold + causal mask (only tile jn-1 straddles the diagonal)
    const int rbase = q0 + (g4 << 2);
    #pragma unroll
    for (int n = 0; n < 4; ++n)
      #pragma unroll
      for (int v = 0; v < 4; ++v) {
        float sv = sc[n][v];
        float vv = sv, ww = 0.f;
        #pragma unroll
        for (int st = 0; st < 4; ++st) {
          vv = vv + FHN_DT * (vv - vv * vv * vv * (1.f / 3.f) - ww + sv);
          ww = (ww + dtau * (vv + FHN_A_)) * wden;
        }
        float lg = vv - 0.5f;
        if (j == jn - 1) {
          int kvi = kv0 + n * 16 + l15;
          if (kvi > rbase + v) lg = -1e9f;
        }
        sc[n][v] = lg;
      }
    // fixed-shift softmax: p = exp(lg - 4); per-lane partial sums only
    #pragma unroll
    for (int n = 0; n < 4; ++n)
      #pragma unroll
      for (int v = 0; v < 4; ++v) {
        float p = __expf(sc[n][v] - 4.0f);
        sc[n][v] = p;
        ssum[v] += p;
      }
    // P -> bf16 -> per-wave swizzled LDS (wave-local RAW)
    #pragma unroll
    for (int n = 0; n < 4; ++n)
      #pragma unroll
      for (int v = 0; v < 4; ++v) {
        int rr = (g4 << 2) + v;
        int c = n * 16 + l15;
        int c16 = (c >> 3) ^ (rr & 7);
        Ps[rr * 64 + c16 * 8 + (c & 7)] = (bf16)sc[n][v];
      }
    // O += P . V
    #pragma unroll
    for (int ks = 0; ks < 2; ++ks) {
      int c16 = (ks * 4 + g4) ^ (l15 & 7);
      bf16x8 pa = *(const bf16x8*)&Ps[l15 * 64 + c16 * 8];
      #pragma unroll
      for (int n = 0; n < 4; ++n) {
        bf16x8 vf = *(const bf16x8*)(vb + (size_t)(n * 16 + l15) * 1024 + kv0 + ks * 32 + g4 * 8);
        o[n] = __builtin_amdgcn_mfma_f32_16x16x32_bf16(pa, vf, o[n], 0, 0, 0);
      }
    }
  }
  // one row-sum reduce per strip (rows live in 16-lane groups)
  #pragma unroll
  for (int v = 0; v < 4; ++v)
    #pragma unroll
    for (int msk = 1; msk < 16; msk <<= 1)
      ssum[v] += __shfl_xor(ssum[v], msk, 64);
  __syncthreads();                 // all Ps reads done -> comb may overwrite
  #pragma unroll
  for (int n = 0; n < 4; ++n)
    #pragma unroll
    for (int v = 0; v < 4; ++v)
      comb[(wid * 16 + (g4 << 2) + v) * 64 + n * 16 + l15] = o[n][v];
  if (l15 == 0) {
    #pragma unroll
    for (int v = 0; v < 4; ++v)
      lsum[wid * 16 + (g4 << 2) + v] = ssum[v];
  }
  __syncthreads();
  // merge: thread t handles (row = t>>4, 4 d-values at dseg = t&15); plain sums
  {
    const int row = t >> 4, dseg = t & 15;
    float L = 0.f;
    f32x4 a = {0.f, 0.f, 0.f, 0.f};
    #pragma unroll
    for (int w = 0; w < 4; ++w) {
      L += lsum[w * 16 + row];
      f32x4 c = *(const f32x4*)&comb[(w * 16 + row) * 64 + dseg * 4];
      a += c;
    }
    const float inv = 1.f / L;
    bf16x4 o4;
    o4[0] = (bf16)(a[0] * inv); o4[1] = (bf16)(a[1] * inv);
    o4[2] = (bf16)(a[2] * inv); o4[3] = (bf16)(a[3] * inv);
    *(bf16x4*)&ctx[(size_t)(b * 1024 + q0 + row) * 1024 + hh * 64 + dseg * 4] = o4;
  }
}

// ---------------------------------------------------------------- launch
extern "C" void kernel_launch(void* const* d_in, const int* in_sizes, int n_in,
                              void* d_out, int out_size, void* d_ws, size_t ws_size,
                              hipStream_t stream) {
  (void)in_sizes; (void)n_in; (void)out_size; (void)ws_size;
  const float* sdr    = (const float*)d_in[0];
  const float* sdr_w  = (const float*)d_in[1];
  const float* sdr_b  = (const float*)d_in[2];
  const float* w_qkv  = (const float*)d_in[3];
  const float* b_qkv  = (const float*)d_in[4];
  const float* w_out  = (const float*)d_in[5];
  const float* b_out  = (const float*)d_in[6];
  const float* ln1_g  = (const float*)d_in[7];
  const float* ln1_b  = (const float*)d_in[8];
  const float* ln2_g  = (const float*)d_in[9];
  const float* ln2_b  = (const float*)d_in[10];
  const float* w_gate = (const float*)d_in[11];
  const float* w_up   = (const float*)d_in[12];
  const float* w_down = (const float*)d_in[13];
  float* out = (float*)d_out;

  char* wsb = (char*)d_ws;
  size_t off = 0;
  auto alloc = [&](size_t bytes) -> void* {
    void* p = (void*)(wsb + off);
    off += (bytes + 255) & ~(size_t)255;
    return p;
  };
  bf16* sdr_w_t  = (bf16*)alloc(1024ull * 2048 * 2);
  bf16* w_qkv_t  = (bf16*)alloc(3072ull * 1024 * 2);
  bf16* w_out_t  = (bf16*)alloc(1024ull * 1024 * 2);
  bf16* w_gate_t = (bf16*)alloc(2816ull * 1024 * 2);
  bf16* w_up_t   = (bf16*)alloc(2816ull * 1024 * 2);
  bf16* w_down_t = (bf16*)alloc(1024ull * 2816 * 2);
  bf16* big_bf   = (bf16*)alloc(2048ull * 2816 * 2);  // sdr_bf16 then act (time-shared)
  bf16* sdr_bf   = big_bf;
  bf16* act      = big_bf;
  float* x       = (float*)alloc(2048ull * 1024 * 4);  // written by LN1
  bf16*  h       = (bf16*)alloc(2048ull * 1024 * 2);   // h1 then h2 (time-shared)
  float* vbuf    = (float*)alloc(2048ull * 1024 * 4);
  bf16*  qb      = (bf16*)alloc(32ull * 1024 * 64 * 2);
  bf16*  kb      = (bf16*)alloc(32ull * 1024 * 64 * 2);
  bf16*  vT      = (bf16*)alloc(32ull * 1024 * 64 * 2);
  bf16*  ctx     = (bf16*)alloc(2048ull * 1024 * 2);
  float* x2      = (float*)alloc(2048ull * 1024 * 4);  // written by LN2
  float* part    = (float*)alloc(2ull * 2048 * 1024 * 4);  // split-K partials (reused 3x)
  float* part1   = part + 2048ull * 1024;

  // fused prep: sdr convert + all 6 weight transposes (one launch)
  k_prep<<<4160, 256, 0, stream>>>(sdr, sdr_bf, sdr_w, w_qkv, w_out, w_gate,
                                   w_up, w_down, sdr_w_t, w_qkv_t, w_out_t,
                                   w_gate_t, w_up_t, w_down_t);

  // x = sdr @ sdr_w + sdr_b  (split-K x2 -> partials; LN1 fuses reduce+bias)
  k_gemm64<<<dim3(16, 16, 2), 256, 0, stream>>>(sdr_bf, sdr_w_t, part, 1024, 2048);
  k_layernorm2<<<2048, 256, 0, stream>>>(part, part1, nullptr, sdr_b, ln1_g, ln1_b, h, x);
  // qkv GEMM with fused split: q,k bf16 [bh][t][d] (q pre-scaled), v fp32 compact
  k_gemm<EPI_QKV><<<dim3(24, 16), 256, 0, stream>>>(h, w_qkv_t, b_qkv, qb, kb, vbuf, 3072, 1024);
  k_transpose_v<<<dim3(32, 2, 32), 256, 0, stream>>>(vbuf, vT);
  // FHN flash attention (64 strips x 32 bh, heavy-first, 4-wave KV split)
  k_attn<<<2048, 256, 0, stream>>>(qb, kb, vT, ctx);
  // x2 = x + ctx @ w_out + b_out  (split-K x2; LN2 fuses reduce+bias+residual)
  k_gemm64<<<dim3(16, 16, 2), 256, 0, stream>>>(ctx, w_out_t, part, 1024, 1024);
  k_layernorm2<<<2048, 256, 0, stream>>>(part, part1, x, b_out, ln2_g, ln2_b, h, x2);
  // act = silu(h2 @ w_gate) * (h2 @ w_up)  (fused, A staged once)
  k_gemm_swiglu<<<dim3(22, 16), 256, 0, stream>>>(h, w_gate_t, w_up_t, act, 2816, 1024);
  // out = x2 + act @ w_down  (split-K x2 + final add)
  k_gemm64<<<dim3(16, 16, 2), 256, 0, stream>>>(act, w_down_t, part, 1024, 2816);
  k_final<<<2048, 256, 0, stream>>>(x2, part, part1, out);
}